// Round 2
// baseline (235.408 us; speedup 1.0000x reference)
//
#include <hip/hip_runtime.h>

#define BB 64
#define SS 512
#define HH 768
#define EE 128
#define TT 4
#define H4 (HH / 4)     // 192 float4 lanes per row
#define NP (EE * TT)    // 512 (entity,token) pairs
#define NROWS (BB * SS) // 32768 enhance rows

// ---------------------------------------------------------------------------
// Single fused kernel.
//   Blocks [0, NROWS):           enhanced[b,s,:] = hidden[b,s,:] + sum of
//                                emb[b,e] over pairs (e,t) with tok==s.
//   Blocks [NROWS, NROWS+B*E):   ee[b,e,:] = 0.25 * sum_t ( hidden[b,s_t,:]
//                                + sum_{pairs p: tok[p]==s_t} emb[b,p>>2,:] )
//                                -- analytically equal to mean of enhanced
//                                rows, so NO dependency on the enhance pass.
// Match discovery: cooperative scan of the 512 ent_tokens pairs per block
// (~3 compares/thread, L1-resident) into a shared list. Replaces the old
// counting-sort index kernel + workspace entirely -> one dispatch, no
// single-block serial prologue, no inter-kernel barrier.
// emb[b,e,:] = type_table[type] + conf*conf_w + conf_b; factored as
// (sum of type rows) + (sum of conf)*conf_w + count*conf_b.
// ---------------------------------------------------------------------------
__global__ __launch_bounds__(H4) void fused_kernel(
    const float* __restrict__ hidden,
    const int* __restrict__ entity_types,   // (B,E)
    const float* __restrict__ conf,         // (B,E)
    const int* __restrict__ ent_tokens,     // (E,T)
    const float* __restrict__ type_table,   // (5,H)
    const float* __restrict__ conf_w,       // (H)
    const float* __restrict__ conf_b,       // (H)
    float* __restrict__ enhanced,           // (B,S,H)
    float* __restrict__ ee) {               // (B,E,H)
  const int tid = threadIdx.x;  // 0..191
  const int blk = blockIdx.x;

  __shared__ int nmatch;
  __shared__ int mlist[NP];  // enhance: entity e; gather: e | (weight<<16)

  if (tid == 0) nmatch = 0;
  __syncthreads();

  if (blk < NROWS) {
    // ------------------------- enhance path -------------------------------
    const int row = blk;
    const int b = row >> 9;          // / SS
    const int s = row & (SS - 1);

    for (int p = tid; p < NP; p += H4) {
      if (ent_tokens[p] == s) {
        const int i = atomicAdd(&nmatch, 1);
        mlist[i] = p >> 2;           // e = pair / T (duplicates preserved)
      }
    }

    // issue the row load while the scan settles
    float4 acc = ((const float4*)hidden)[(size_t)row * H4 + tid];
    __syncthreads();

    const int n = nmatch;
    if (n > 0) {
      const float4 wv = ((const float4*)conf_w)[tid];
      const float4 bv = ((const float4*)conf_b)[tid];
      float4 tsum = make_float4(0.f, 0.f, 0.f, 0.f);
      float csum = 0.f;
      for (int j = 0; j < n; ++j) {
        const int e = mlist[j];
        const int ty = entity_types[b * EE + e];
        csum += conf[b * EE + e];
        const float4 tv = ((const float4*)type_table)[ty * H4 + tid];
        tsum.x += tv.x;
        tsum.y += tv.y;
        tsum.z += tv.z;
        tsum.w += tv.w;
      }
      const float fn = (float)n;
      acc.x += tsum.x + fmaf(csum, wv.x, fn * bv.x);
      acc.y += tsum.y + fmaf(csum, wv.y, fn * bv.y);
      acc.z += tsum.z + fmaf(csum, wv.z, fn * bv.z);
      acc.w += tsum.w + fmaf(csum, wv.w, fn * bv.w);
    }
    ((float4*)enhanced)[(size_t)row * H4 + tid] = acc;
  } else {
    // ------------------------ gather/mean path ----------------------------
    const int be = blk - NROWS;
    const int b = be >> 7;           // / EE
    const int e = be & (EE - 1);

    const int s0 = ent_tokens[e * TT + 0];
    const int s1 = ent_tokens[e * TT + 1];
    const int s2 = ent_tokens[e * TT + 2];
    const int s3 = ent_tokens[e * TT + 3];

    // weight w = how many of this entity's 4 tokens pair p lands on
    for (int p = tid; p < NP; p += H4) {
      const int tok = ent_tokens[p];
      const int w = (tok == s0) + (tok == s1) + (tok == s2) + (tok == s3);
      if (w) {
        const int i = atomicAdd(&nmatch, 1);
        mlist[i] = (p >> 2) | (w << 16);
      }
    }

    const float4* hb = (const float4*)hidden + (size_t)b * SS * H4;
    const float4 v0 = hb[(size_t)s0 * H4 + tid];
    const float4 v1 = hb[(size_t)s1 * H4 + tid];
    const float4 v2 = hb[(size_t)s2 * H4 + tid];
    const float4 v3 = hb[(size_t)s3 * H4 + tid];
    float4 acc;
    acc.x = (v0.x + v1.x) + (v2.x + v3.x);
    acc.y = (v0.y + v1.y) + (v2.y + v3.y);
    acc.z = (v0.z + v1.z) + (v2.z + v3.z);
    acc.w = (v0.w + v1.w) + (v2.w + v3.w);
    __syncthreads();

    const int n = nmatch;
    const float4 wv = ((const float4*)conf_w)[tid];
    const float4 bv = ((const float4*)conf_b)[tid];
    float4 tsum = make_float4(0.f, 0.f, 0.f, 0.f);
    float csum = 0.f;
    float wsum = 0.f;
    for (int j = 0; j < n; ++j) {
      const int packed = mlist[j];
      const int e2 = packed & 0xffff;
      const float fw = (float)(packed >> 16);
      const int ty = entity_types[b * EE + e2];
      const float c = conf[b * EE + e2];
      csum += fw * c;
      wsum += fw;
      const float4 tv = ((const float4*)type_table)[ty * H4 + tid];
      tsum.x += fw * tv.x;
      tsum.y += fw * tv.y;
      tsum.z += fw * tv.z;
      tsum.w += fw * tv.w;
    }
    float4 o;
    o.x = 0.25f * (acc.x + tsum.x + fmaf(csum, wv.x, wsum * bv.x));
    o.y = 0.25f * (acc.y + tsum.y + fmaf(csum, wv.y, wsum * bv.y));
    o.z = 0.25f * (acc.z + tsum.z + fmaf(csum, wv.z, wsum * bv.z));
    o.w = 0.25f * (acc.w + tsum.w + fmaf(csum, wv.w, wsum * bv.w));
    ((float4*)ee)[(size_t)be * H4 + tid] = o;
  }
}

extern "C" void kernel_launch(void* const* d_in, const int* in_sizes, int n_in,
                              void* d_out, int out_size, void* d_ws,
                              size_t ws_size, hipStream_t stream) {
  const float* hidden = (const float*)d_in[0];      // (B,S,H) fp32
  const int* entity_types = (const int*)d_in[1];    // (B,E) i32
  const float* conf = (const float*)d_in[2];        // (B,E) fp32
  const int* ent_tokens = (const int*)d_in[3];      // (E,T) i32
  const float* type_table = (const float*)d_in[4];  // (5,H) fp32
  const float* conf_w = (const float*)d_in[5];      // (1,H) fp32
  const float* conf_b = (const float*)d_in[6];      // (H) fp32

  float* enhanced = (float*)d_out;                   // (B,S,H)
  float* ee = (float*)d_out + (size_t)BB * SS * HH;  // (B,E,H)

  fused_kernel<<<NROWS + BB * EE, H4, 0, stream>>>(
      hidden, entity_types, conf, ent_tokens, type_table, conf_w, conf_b,
      enhanced, ee);
}